// Round 3
// baseline (148.103 us; speedup 1.0000x reference)
//
#include <hip/hip_runtime.h>

// Problem constants
#define MD 4
#define DD 9            // 2*MD+1
#define B  4
#define C  64
#define H  64
#define W  128
#define HW (H * W)      // 8192 floats per (i,j) slice of one (b,c)

// Padded LDS tile for the target plane: 4 zero rows/cols on each side.
#define LROW  136       // 4 + 128 + 4
#define LROWS 72        // 4 + 64  + 4
#define LDS_F (LROWS * LROW)   // 9792 floats = 39,168 B -> up to 4 blocks/CU

typedef float f32x4 __attribute__((ext_vector_type(4)));

__device__ __forceinline__ f32x4 lrelu4(f32x4 p) {
    f32x4 o;
    o.x = fmaxf(p.x, 0.1f * p.x);
    o.y = fmaxf(p.y, 0.1f * p.y);
    o.z = fmaxf(p.z, 0.1f * p.z);
    o.w = fmaxf(p.w, 0.1f * p.w);
    return o;
}

// Block owns 3 consecutive units (bc, i) sharing one bc plane.
// Per unit: stage tgt plane into LDS shifted by (8-i) columns inside a
// zero-padded 72x136 tile -> window read is ONE aligned ds_read_b128 at
// lds[y+j][x+4], no i-dependence, OOB zeros from padding.
// j-outer / row-chunk-inner => block stores march linearly through 288 KB.
__global__ __launch_bounds__(256) void corr_kernel(const float* __restrict__ ref,
                                                   const float* __restrict__ tgt,
                                                   float* __restrict__ out) {
    __shared__ __align__(16) float ldsT[LDS_F];

    const unsigned t  = threadIdx.x;
    const unsigned bc = blockIdx.x / 3u;          // 0..255
    const unsigned i0 = (blockIdx.x % 3u) * 3u;   // {0,3,6}
    const unsigned x4 = t & 31u;
    const unsigned x  = x4 * 4u;
    const unsigned yw = t >> 5;                   // 0..7

    const float* refp = ref + (size_t)bc * HW;
    const float* tgtp = tgt + (size_t)bc * HW;

    // Hoist this thread's 8 ref float4s (y = s*8 + yw) into registers once.
    f32x4 r8[8];
    #pragma unroll
    for (int s = 0; s < 8; ++s)
        r8[s] = *reinterpret_cast<const f32x4*>(refp + (size_t)(s * 8 + yw) * W + x);

    for (unsigned k = 0; k < 3; ++k) {
        const unsigned i  = i0 + k;
        const unsigned sh = 8u - i;   // column shift: lds[r][c+sh] = tgt[r][c]

        __syncthreads();  // previous unit's readers done before we re-zero

        // Zero the padded tile (2448 float4)
        #pragma unroll
        for (int z = 0; z < 10; ++z) {
            unsigned idx = (unsigned)z * 256u + t;
            if (idx < LDS_F / 4)
                reinterpret_cast<f32x4*>(ldsT)[idx] = (f32x4){0.f, 0.f, 0.f, 0.f};
        }
        __syncthreads();

        // Stage tgt plane shifted by sh (scalar LDS writes: shift breaks
        // 16B alignment; cost amortized 1:72 vs compute iterations)
        #pragma unroll
        for (int z = 0; z < 8; ++z) {
            unsigned idx = (unsigned)z * 256u + t;   // f4 index in plane (2048)
            unsigned row = idx >> 5;                 // 0..63
            unsigned c4  = idx & 31u;
            f32x4 g = *reinterpret_cast<const f32x4*>(tgtp + (size_t)idx * 4u);
            unsigned base = (row + MD) * LROW + c4 * 4u + sh;
            ldsT[base + 0] = g.x;
            ldsT[base + 1] = g.y;
            ldsT[base + 2] = g.z;
            ldsT[base + 3] = g.w;
        }
        __syncthreads();

        float* outu = out + ((size_t)bc * (DD * DD) + (size_t)i * DD) * HW;
        #pragma unroll
        for (int j = 0; j < DD; ++j) {
            float* oj = outu + (size_t)j * HW;
            #pragma unroll
            for (int s = 0; s < 8; ++s) {
                const unsigned y = (unsigned)s * 8u + yw;
                const f32x4 w = *reinterpret_cast<const f32x4*>(
                    &ldsT[(y + (unsigned)j) * LROW + x + 4u]);
                __builtin_nontemporal_store(
                    lrelu4(r8[s] * w),
                    reinterpret_cast<f32x4*>(oj + (size_t)y * W + x));
            }
        }
    }
}

extern "C" void kernel_launch(void* const* d_in, const int* in_sizes, int n_in,
                              void* d_out, int out_size, void* d_ws, size_t ws_size,
                              hipStream_t stream) {
    const float* ref = (const float*)d_in[0];
    const float* tgt = (const float*)d_in[1];
    float* out = (float*)d_out;

    // 256 bc-planes x 3 i-triples = 768 blocks = exactly 3 resident per CU,
    // each handling 3 (bc,i) units -> zero dispatch tail, balanced.
    corr_kernel<<<768, 256, 0, stream>>>(ref, tgt, out);
}